// Round 18
// baseline (51.781 us; speedup 1.0000x reference)
//
#include <hip/hip_runtime.h>
#include <math.h>

// QuantumGenerator: 4-qubit, 2-layer StronglyEntanglingLayers circuit + Linear(4,4).
// out_j(x) = sum_{p in {I,Z,Y}^4} D_j[p] * prod_w f_{p_w}(x_w),  f = (1, cos, -sin).
// qg_precompute (1 block, shfl-parallel): builds 81x4 coefficient table D in d_ws.
// qg_main (R18): E=4 via TWO packed v2f lanes (P: elems A,B; Q: elems C,D).
//   v_pk_fma_f32 throughout; per-wave s_load stream + waits amortized over 256
//   elems/wave. All named variables; __launch_bounds__(256,3) avoids spills.

typedef float v2f __attribute__((ext_vector_type(2)));

__device__ __forceinline__ v2f splat2(float s) { v2f r; r.x = s; r.y = s; return r; }

__global__ __launch_bounds__(256) void qg_precompute(
    const float* __restrict__ qw,   // [2][4][3] (phi, theta, omega)
    const float* __restrict__ Wm,   // [4][4]
    const float* __restrict__ bv,   // [4]
    float* __restrict__ Dcoef)      // [81][4]
{
  __shared__ float  gm[24][8];      // per-gate 2x2 complex matrix
  __shared__ float2 Ul[16][16];     // U[k][col]
  __shared__ float  wj[4][16];
  __shared__ float2 A[4][16][16];
  const int tid = threadIdx.x;

  if (tid < 24) {
    const float phi = qw[tid*3 + 0];
    const float th  = qw[tid*3 + 1];
    const float om  = qw[tid*3 + 2];
    const float st = __sinf(0.5f*th),       ct = __cosf(0.5f*th);
    const float sa = __sinf(0.5f*(phi+om)), ca = __cosf(0.5f*(phi+om));
    const float sd = __sinf(0.5f*(phi-om)), cd = __cosf(0.5f*(phi-om));
    gm[tid][0] =  ca*ct; gm[tid][1] = -sa*ct;   // m00
    gm[tid][2] = -cd*st; gm[tid][3] = -sd*st;   // m01
    gm[tid][4] =  cd*st; gm[tid][5] = -sd*st;   // m10
    gm[tid][6] =  ca*ct; gm[tid][7] =  sa*ct;   // m11
  }
  if (tid >= 192) {
    const int j = (tid - 192) >> 4, k = tid & 15;
    float s = 0.f;
    #pragma unroll
    for (int i = 0; i < 4; ++i)
      s += Wm[j*4 + i] * (((k >> (3 - i)) & 1) ? -1.f : 1.f);
    wj[j][k] = s;
  }
  __syncthreads();

  {  // U build: one matrix element per thread, shfl butterflies (16-lane groups)
    const int col = tid >> 4, row = tid & 15;
    float vr = (row == col) ? 1.f : 0.f, vi = 0.f;
    #pragma unroll
    for (int l = 0; l < 2; ++l) {
      #pragma unroll
      for (int w = 0; w < 4; ++w) {
        const int g = l*4 + w;
        const float m00r = gm[g][0], m00i = gm[g][1];
        const float m01r = gm[g][2], m01i = gm[g][3];
        const float m10r = gm[g][4], m10i = gm[g][5];
        const float m11r = gm[g][6], m11i = gm[g][7];
        const int mask = 8 >> w;
        const float pr = __shfl_xor(vr, mask);
        const float pi = __shfl_xor(vi, mask);
        float nr, ni;
        if (!(row & mask)) {
          nr = m00r*vr - m00i*vi + m01r*pr - m01i*pi;
          ni = m00r*vi + m00i*vr + m01r*pi + m01i*pr;
        } else {
          nr = m10r*pr - m10i*pi + m11r*vr - m11i*vi;
          ni = m10r*pi + m10i*pr + m11r*vi + m11i*vr;
        }
        vr = nr; vi = ni;
      }
      const int r = l + 1;  // StronglyEntanglingLayers ranges for 2 layers
      #pragma unroll
      for (int w = 0; w < 4; ++w) {
        const int t  = (w + r) & 3;
        const int cm = 8 >> w, tm = 8 >> t;
        const float pr = __shfl_xor(vr, tm);
        const float pi = __shfl_xor(vi, tm);
        if (row & cm) { vr = pr; vi = pi; }
      }
    }
    Ul[row][col] = make_float2(vr, vi);
  }
  __syncthreads();

  {  // A[j][s][t] = sum_k conj(U[k][s]) wj[j][k] U[k][t]
    const int s = tid >> 4, t = tid & 15;
    float ar[4] = {0,0,0,0}, ai[4] = {0,0,0,0};
    #pragma unroll
    for (int k = 0; k < 16; ++k) {
      const float2 us = Ul[k][s], ut = Ul[k][t];
      const float pr = us.x*ut.x + us.y*ut.y;
      const float pi = us.x*ut.y - us.y*ut.x;
      #pragma unroll
      for (int j = 0; j < 4; ++j) { ar[j] += wj[j][k]*pr; ai[j] += wj[j][k]*pi; }
    }
    #pragma unroll
    for (int j = 0; j < 4; ++j) A[j][s][t] = make_float2(ar[j], ai[j]);
  }
  __syncthreads();

  // D_j[p] = (1/16) Tr(A_j sigma_p), sigma in {I,Z,Y}^4
  for (int item = tid; item < 324; item += 256) {
    const int j = item / 81, p = item % 81;
    const int p1 = p / 27, p2 = (p / 9) % 3, p3 = (p / 3) % 3, p4 = p % 3;
    int ym = 0, ny = 0;
    if (p1 == 2) { ym |= 8; ++ny; }
    if (p2 == 2) { ym |= 4; ++ny; }
    if (p3 == 2) { ym |= 2; ++ny; }
    if (p4 == 2) { ym |= 1; ++ny; }
    float sum = 0.f;
    for (int t = 0; t < 16; ++t) {
      const int t0 = (t>>3)&1, t1 = (t>>2)&1, t2 = (t>>1)&1, t3 = t&1;
      float sgn = 1.f;
      if      (p1 == 1) sgn *= t0 ? -1.f : 1.f;
      else if (p1 == 2) sgn *= t0 ?  1.f : -1.f;
      if      (p2 == 1) sgn *= t1 ? -1.f : 1.f;
      else if (p2 == 2) sgn *= t1 ?  1.f : -1.f;
      if      (p3 == 1) sgn *= t2 ? -1.f : 1.f;
      else if (p3 == 2) sgn *= t2 ?  1.f : -1.f;
      if      (p4 == 1) sgn *= t3 ? -1.f : 1.f;
      else if (p4 == 2) sgn *= t3 ?  1.f : -1.f;
      const float2 ae = A[j][t ^ ym][t];
      const int m = ny & 3;
      const float re = (m == 0) ? ae.x : (m == 1) ? -ae.y : (m == 2) ? -ae.x : ae.y;
      sum += sgn * re;
    }
    sum *= 0.0625f;
    if (p == 0) sum += bv[j];
    Dcoef[p*4 + j] = sum;
  }
}

#define QG_CONST __attribute__((address_space(4)))

__global__ __launch_bounds__(256, 3) void qg_main(
    const float4* __restrict__ noise,   // [B] float4 (x0..x3)
    const float*  __restrict__ Dg,      // [81][4] coefficient table
    float4* __restrict__ out,           // [B] float4
    int B)
{
  const QG_CONST float* D = (const QG_CONST float*)(unsigned long long)Dg;

  const int tid = threadIdx.x;
  const int ia  = blockIdx.x * 1024 + tid;  // elem A
  const int ib  = ia + 256;                 // elem B
  const int ic  = ia + 512;                 // elem C
  const int id_ = ia + 768;                 // elem D
  const int Bm1 = B - 1;
  const float4 xa = noise[min(ia,  Bm1)];
  const float4 xb = noise[min(ib,  Bm1)];
  const float4 xc = noise[min(ic,  Bm1)];
  const float4 xd = noise[min(id_, Bm1)];

  // Fast trig, packed into P = {A,B} and Q = {C,D} lanes.
  v2f s0P,c0P,s1P,c1P,s2P,c2P,s3P,c3P;
  v2f s0Q,c0Q,s1Q,c1Q,s2Q,c2Q,s3Q,c3Q;
  s0P.x = __sinf(xa.x); s0P.y = __sinf(xb.x); c0P.x = __cosf(xa.x); c0P.y = __cosf(xb.x);
  s1P.x = __sinf(xa.y); s1P.y = __sinf(xb.y); c1P.x = __cosf(xa.y); c1P.y = __cosf(xb.y);
  s2P.x = __sinf(xa.z); s2P.y = __sinf(xb.z); c2P.x = __cosf(xa.z); c2P.y = __cosf(xb.z);
  s3P.x = __sinf(xa.w); s3P.y = __sinf(xb.w); c3P.x = __cosf(xa.w); c3P.y = __cosf(xb.w);
  s0Q.x = __sinf(xc.x); s0Q.y = __sinf(xd.x); c0Q.x = __cosf(xc.x); c0Q.y = __cosf(xd.x);
  s1Q.x = __sinf(xc.y); s1Q.y = __sinf(xd.y); c1Q.x = __cosf(xc.y); c1Q.y = __cosf(xd.y);
  s2Q.x = __sinf(xc.z); s2Q.y = __sinf(xd.z); c2Q.x = __cosf(xc.z); c2Q.y = __cosf(xd.z);
  s3Q.x = __sinf(xc.w); s3Q.y = __sinf(xd.w); c3Q.x = __cosf(xc.w); c3Q.y = __cosf(xd.w);

  // f = (1, cos, -sin); g12[a]=f1[a/3]*f2[a%3]; g34[b]=f3[b/3]*f4[b%3]
  const v2f g34_1P =  c3P,         g34_2P = -s3P,
            g34_3P =  c2P,         g34_4P =  c2P*c3P, g34_5P = -(c2P*s3P),
            g34_6P = -s2P,         g34_7P = -(s2P*c3P), g34_8P = s2P*s3P;
  const v2f g12_1P =  c1P,         g12_2P = -s1P,
            g12_3P =  c0P,         g12_4P =  c0P*c1P, g12_5P = -(c0P*s1P),
            g12_6P = -s0P,         g12_7P = -(s0P*c1P), g12_8P = s0P*s1P;
  const v2f g34_1Q =  c3Q,         g34_2Q = -s3Q,
            g34_3Q =  c2Q,         g34_4Q =  c2Q*c3Q, g34_5Q = -(c2Q*s3Q),
            g34_6Q = -s2Q,         g34_7Q = -(s2Q*c3Q), g34_8Q = s2Q*s3Q;
  const v2f g12_1Q =  c1Q,         g12_2Q = -s1Q,
            g12_3Q =  c0Q,         g12_4Q =  c0Q*c1Q, g12_5Q = -(c0Q*s1Q),
            g12_6Q = -s0Q,         g12_7Q = -(s0Q*c1Q), g12_8Q = s0Q*s1Q;

  v2f h0P, h1P, h2P, h3P, acc0P, acc1P, acc2P, acc3P;
  v2f h0Q, h1Q, h2Q, h3Q, acc0Q, acc1Q, acc2Q, acc3Q;

#define FMA2(a,b,c) __builtin_elementwise_fma((a), (b), (c))
#define HT(a,b,gP,gQ) {                                               \
    const v2f qx = splat2(D[((a)*9+(b))*4+0]);                        \
    const v2f qy = splat2(D[((a)*9+(b))*4+1]);                        \
    const v2f qz = splat2(D[((a)*9+(b))*4+2]);                        \
    const v2f qw_ = splat2(D[((a)*9+(b))*4+3]);                       \
    h0P = FMA2(qx,  (gP), h0P); h0Q = FMA2(qx,  (gQ), h0Q);           \
    h1P = FMA2(qy,  (gP), h1P); h1Q = FMA2(qy,  (gQ), h1Q);           \
    h2P = FMA2(qz,  (gP), h2P); h2Q = FMA2(qz,  (gQ), h2Q);           \
    h3P = FMA2(qw_, (gP), h3P); h3Q = FMA2(qw_, (gQ), h3Q); }
#define HB(a) {                                                       \
    h0P = splat2(D[(a)*36+0]); h0Q = h0P;                             \
    h1P = splat2(D[(a)*36+1]); h1Q = h1P;                             \
    h2P = splat2(D[(a)*36+2]); h2Q = h2P;                             \
    h3P = splat2(D[(a)*36+3]); h3Q = h3P; }                           \
    HT(a,1,g34_1P,g34_1Q) HT(a,2,g34_2P,g34_2Q) HT(a,3,g34_3P,g34_3Q) \
    HT(a,4,g34_4P,g34_4Q) HT(a,5,g34_5P,g34_5Q) HT(a,6,g34_6P,g34_6Q) \
    HT(a,7,g34_7P,g34_7Q) HT(a,8,g34_8P,g34_8Q)
#define ACC(gP,gQ) {                                                  \
    acc0P = FMA2((gP), h0P, acc0P); acc0Q = FMA2((gQ), h0Q, acc0Q);   \
    acc1P = FMA2((gP), h1P, acc1P); acc1Q = FMA2((gQ), h1Q, acc1Q);   \
    acc2P = FMA2((gP), h2P, acc2P); acc2Q = FMA2((gQ), h2Q, acc2Q);   \
    acc3P = FMA2((gP), h3P, acc3P); acc3Q = FMA2((gQ), h3Q, acc3Q); }

  HB(0) acc0P = h0P; acc1P = h1P; acc2P = h2P; acc3P = h3P;
        acc0Q = h0Q; acc1Q = h1Q; acc2Q = h2Q; acc3Q = h3Q;
  HB(1) ACC(g12_1P, g12_1Q)
  HB(2) ACC(g12_2P, g12_2Q)
  HB(3) ACC(g12_3P, g12_3Q)
  HB(4) ACC(g12_4P, g12_4Q)
  HB(5) ACC(g12_5P, g12_5Q)
  HB(6) ACC(g12_6P, g12_6Q)
  HB(7) ACC(g12_7P, g12_7Q)
  HB(8) ACC(g12_8P, g12_8Q)

#undef HT
#undef HB
#undef ACC
#undef FMA2

  if (ia < B)
    out[ia]  = make_float4(fabsf(acc0P.x) + 0.001f, acc1P.x, acc2P.x, acc3P.x);
  if (ib < B)
    out[ib]  = make_float4(fabsf(acc0P.y) + 0.001f, acc1P.y, acc2P.y, acc3P.y);
  if (ic < B)
    out[ic]  = make_float4(fabsf(acc0Q.x) + 0.001f, acc1Q.x, acc2Q.x, acc3Q.x);
  if (id_ < B)
    out[id_] = make_float4(fabsf(acc0Q.y) + 0.001f, acc1Q.y, acc2Q.y, acc3Q.y);
}

extern "C" void kernel_launch(void* const* d_in, const int* in_sizes, int n_in,
                              void* d_out, int out_size, void* d_ws, size_t ws_size,
                              hipStream_t stream) {
  const float* noise = (const float*)d_in[0];   // [B,4]
  const float* qw    = (const float*)d_in[1];   // [2,4,3]
  const float* Wm    = (const float*)d_in[2];   // [4,4]
  const float* bv    = (const float*)d_in[3];   // [4]
  float* Dcoef = (float*)d_ws;                  // 324 floats
  const int B = in_sizes[0] / 4;

  hipLaunchKernelGGL(qg_precompute, dim3(1), dim3(256), 0, stream, qw, Wm, bv, Dcoef);

  const int blocks = (B + 1023) / 1024;         // 1024 for B = 1048576
  hipLaunchKernelGGL(qg_main, dim3(blocks), dim3(256), 0, stream,
                     (const float4*)noise, (const float*)Dcoef, (float4*)d_out, B);
}

// Round 19
// 22.201 us; speedup vs baseline: 2.3323x; 2.3323x over previous
//
#include <hip/hip_runtime.h>
#include <math.h>

// QuantumGenerator: 4-qubit, 2-layer StronglyEntanglingLayers circuit + Linear(4,4).
// out_j(x) = sum_{p in {I,Z,Y}^4} D_j[p] * prod_w f_{p_w}(x_w),  f = (1, cos, -sin).
// qg_precompute (1 block, shfl-parallel): builds 81x4 coefficient table D in d_ws.
// qg_main (R16 configuration == measured best, 22.25us): E=2 elements/thread as
//   ext_vector_type(2) floats -> v_pk_fma_f32 (2x fp32/instr); coefficients via
//   constant-AS s_loads (SGPR operands, splats folded); fast hardware trig.
// Ladder: E=1 24.8us | E=2 packed 22.25us | E=4 spills (VGPR=40, +13MB scratch).

typedef float v2f __attribute__((ext_vector_type(2)));

__device__ __forceinline__ v2f splat2(float s) { v2f r; r.x = s; r.y = s; return r; }

__global__ __launch_bounds__(256) void qg_precompute(
    const float* __restrict__ qw,   // [2][4][3] (phi, theta, omega)
    const float* __restrict__ Wm,   // [4][4]
    const float* __restrict__ bv,   // [4]
    float* __restrict__ Dcoef)      // [81][4]
{
  __shared__ float  gm[24][8];      // per-gate 2x2 complex matrix
  __shared__ float2 Ul[16][16];     // U[k][col]
  __shared__ float  wj[4][16];
  __shared__ float2 A[4][16][16];
  const int tid = threadIdx.x;

  if (tid < 24) {
    const float phi = qw[tid*3 + 0];
    const float th  = qw[tid*3 + 1];
    const float om  = qw[tid*3 + 2];
    const float st = __sinf(0.5f*th),       ct = __cosf(0.5f*th);
    const float sa = __sinf(0.5f*(phi+om)), ca = __cosf(0.5f*(phi+om));
    const float sd = __sinf(0.5f*(phi-om)), cd = __cosf(0.5f*(phi-om));
    gm[tid][0] =  ca*ct; gm[tid][1] = -sa*ct;   // m00
    gm[tid][2] = -cd*st; gm[tid][3] = -sd*st;   // m01
    gm[tid][4] =  cd*st; gm[tid][5] = -sd*st;   // m10
    gm[tid][6] =  ca*ct; gm[tid][7] =  sa*ct;   // m11
  }
  if (tid >= 192) {
    const int j = (tid - 192) >> 4, k = tid & 15;
    float s = 0.f;
    #pragma unroll
    for (int i = 0; i < 4; ++i)
      s += Wm[j*4 + i] * (((k >> (3 - i)) & 1) ? -1.f : 1.f);
    wj[j][k] = s;
  }
  __syncthreads();

  {  // U build: one matrix element per thread, shfl butterflies (16-lane groups)
    const int col = tid >> 4, row = tid & 15;
    float vr = (row == col) ? 1.f : 0.f, vi = 0.f;
    #pragma unroll
    for (int l = 0; l < 2; ++l) {
      #pragma unroll
      for (int w = 0; w < 4; ++w) {
        const int g = l*4 + w;
        const float m00r = gm[g][0], m00i = gm[g][1];
        const float m01r = gm[g][2], m01i = gm[g][3];
        const float m10r = gm[g][4], m10i = gm[g][5];
        const float m11r = gm[g][6], m11i = gm[g][7];
        const int mask = 8 >> w;
        const float pr = __shfl_xor(vr, mask);
        const float pi = __shfl_xor(vi, mask);
        float nr, ni;
        if (!(row & mask)) {
          nr = m00r*vr - m00i*vi + m01r*pr - m01i*pi;
          ni = m00r*vi + m00i*vr + m01r*pi + m01i*pr;
        } else {
          nr = m10r*pr - m10i*pi + m11r*vr - m11i*vi;
          ni = m10r*pi + m10i*pr + m11r*vi + m11i*vr;
        }
        vr = nr; vi = ni;
      }
      const int r = l + 1;  // StronglyEntanglingLayers ranges for 2 layers
      #pragma unroll
      for (int w = 0; w < 4; ++w) {
        const int t  = (w + r) & 3;
        const int cm = 8 >> w, tm = 8 >> t;
        const float pr = __shfl_xor(vr, tm);
        const float pi = __shfl_xor(vi, tm);
        if (row & cm) { vr = pr; vi = pi; }
      }
    }
    Ul[row][col] = make_float2(vr, vi);
  }
  __syncthreads();

  {  // A[j][s][t] = sum_k conj(U[k][s]) wj[j][k] U[k][t]
    const int s = tid >> 4, t = tid & 15;
    float ar[4] = {0,0,0,0}, ai[4] = {0,0,0,0};
    #pragma unroll
    for (int k = 0; k < 16; ++k) {
      const float2 us = Ul[k][s], ut = Ul[k][t];
      const float pr = us.x*ut.x + us.y*ut.y;
      const float pi = us.x*ut.y - us.y*ut.x;
      #pragma unroll
      for (int j = 0; j < 4; ++j) { ar[j] += wj[j][k]*pr; ai[j] += wj[j][k]*pi; }
    }
    #pragma unroll
    for (int j = 0; j < 4; ++j) A[j][s][t] = make_float2(ar[j], ai[j]);
  }
  __syncthreads();

  // D_j[p] = (1/16) Tr(A_j sigma_p), sigma in {I,Z,Y}^4
  for (int item = tid; item < 324; item += 256) {
    const int j = item / 81, p = item % 81;
    const int p1 = p / 27, p2 = (p / 9) % 3, p3 = (p / 3) % 3, p4 = p % 3;
    int ym = 0, ny = 0;
    if (p1 == 2) { ym |= 8; ++ny; }
    if (p2 == 2) { ym |= 4; ++ny; }
    if (p3 == 2) { ym |= 2; ++ny; }
    if (p4 == 2) { ym |= 1; ++ny; }
    float sum = 0.f;
    for (int t = 0; t < 16; ++t) {
      const int t0 = (t>>3)&1, t1 = (t>>2)&1, t2 = (t>>1)&1, t3 = t&1;
      float sgn = 1.f;
      if      (p1 == 1) sgn *= t0 ? -1.f : 1.f;
      else if (p1 == 2) sgn *= t0 ?  1.f : -1.f;
      if      (p2 == 1) sgn *= t1 ? -1.f : 1.f;
      else if (p2 == 2) sgn *= t1 ?  1.f : -1.f;
      if      (p3 == 1) sgn *= t2 ? -1.f : 1.f;
      else if (p3 == 2) sgn *= t2 ?  1.f : -1.f;
      if      (p4 == 1) sgn *= t3 ? -1.f : 1.f;
      else if (p4 == 2) sgn *= t3 ?  1.f : -1.f;
      const float2 ae = A[j][t ^ ym][t];
      const int m = ny & 3;
      const float re = (m == 0) ? ae.x : (m == 1) ? -ae.y : (m == 2) ? -ae.x : ae.y;
      sum += sgn * re;
    }
    sum *= 0.0625f;
    if (p == 0) sum += bv[j];
    Dcoef[p*4 + j] = sum;
  }
}

#define QG_CONST __attribute__((address_space(4)))

__global__ __launch_bounds__(256, 4) void qg_main(
    const float4* __restrict__ noise,   // [B] float4 (x0..x3)
    const float*  __restrict__ Dg,      // [81][4] coefficient table
    float4* __restrict__ out,           // [B] float4
    int B)
{
  // Constant-AS view of D: scalar dereferences compile to s_load (SMEM pipe).
  const QG_CONST float* D = (const QG_CONST float*)(unsigned long long)Dg;

  const int tid = threadIdx.x;
  const int ia  = blockIdx.x * 512 + tid;   // elem A
  const int ib  = ia + 256;                 // elem B
  const int Bm1 = B - 1;
  const float4 xa = noise[min(ia, Bm1)];
  const float4 xb = noise[min(ib, Bm1)];

  // Scalar fast trig (v_sin_f32/v_cos_f32), then pack per-wire vectors.
  v2f s0v, c0v, s1v, c1v, s2v, c2v, s3v, c3v;
  s0v.x = __sinf(xa.x); s0v.y = __sinf(xb.x);
  c0v.x = __cosf(xa.x); c0v.y = __cosf(xb.x);
  s1v.x = __sinf(xa.y); s1v.y = __sinf(xb.y);
  c1v.x = __cosf(xa.y); c1v.y = __cosf(xb.y);
  s2v.x = __sinf(xa.z); s2v.y = __sinf(xb.z);
  c2v.x = __cosf(xa.z); c2v.y = __cosf(xb.z);
  s3v.x = __sinf(xa.w); s3v.y = __sinf(xb.w);
  c3v.x = __cosf(xa.w); c3v.y = __cosf(xb.w);

  // f = (1, cos, -sin); g12[a]=f1[a/3]*f2[a%3]; g34[b]=f3[b/3]*f4[b%3]
  const v2f g34_1 =  c3v,       g34_2 = -s3v,
            g34_3 =  c2v,       g34_4 =  c2v*c3v, g34_5 = -(c2v*s3v),
            g34_6 = -s2v,       g34_7 = -(s2v*c3v), g34_8 = s2v*s3v;
  const v2f g12_1 =  c1v,       g12_2 = -s1v,
            g12_3 =  c0v,       g12_4 =  c0v*c1v, g12_5 = -(c0v*s1v),
            g12_6 = -s0v,       g12_7 = -(s0v*c1v), g12_8 = s0v*s1v;

  v2f h0, h1, h2, h3, acc0, acc1, acc2, acc3;

#define FMA2(a,b,c) __builtin_elementwise_fma((a), (b), (c))
#define HT(a,b,g) {                                                  \
    const float qx = D[((a)*9+(b))*4+0], qy = D[((a)*9+(b))*4+1];    \
    const float qz = D[((a)*9+(b))*4+2], qw_ = D[((a)*9+(b))*4+3];   \
    h0 = FMA2(splat2(qx),  (g), h0); h1 = FMA2(splat2(qy),  (g), h1); \
    h2 = FMA2(splat2(qz),  (g), h2); h3 = FMA2(splat2(qw_), (g), h3); }
#define HB(a) {                                                      \
    h0 = splat2(D[(a)*36+0]); h1 = splat2(D[(a)*36+1]);              \
    h2 = splat2(D[(a)*36+2]); h3 = splat2(D[(a)*36+3]); }            \
    HT(a,1,g34_1) HT(a,2,g34_2) HT(a,3,g34_3) HT(a,4,g34_4)          \
    HT(a,5,g34_5) HT(a,6,g34_6) HT(a,7,g34_7) HT(a,8,g34_8)
#define ACC(g) { acc0 = FMA2((g), h0, acc0); acc1 = FMA2((g), h1, acc1); \
                 acc2 = FMA2((g), h2, acc2); acc3 = FMA2((g), h3, acc3); }

  HB(0) acc0 = h0; acc1 = h1; acc2 = h2; acc3 = h3;
  HB(1) ACC(g12_1)
  HB(2) ACC(g12_2)
  HB(3) ACC(g12_3)
  HB(4) ACC(g12_4)
  HB(5) ACC(g12_5)
  HB(6) ACC(g12_6)
  HB(7) ACC(g12_7)
  HB(8) ACC(g12_8)

#undef HT
#undef HB
#undef ACC
#undef FMA2

  if (ia < B)
    out[ia] = make_float4(fabsf(acc0.x) + 0.001f, acc1.x, acc2.x, acc3.x);
  if (ib < B)
    out[ib] = make_float4(fabsf(acc0.y) + 0.001f, acc1.y, acc2.y, acc3.y);
}

extern "C" void kernel_launch(void* const* d_in, const int* in_sizes, int n_in,
                              void* d_out, int out_size, void* d_ws, size_t ws_size,
                              hipStream_t stream) {
  const float* noise = (const float*)d_in[0];   // [B,4]
  const float* qw    = (const float*)d_in[1];   // [2,4,3]
  const float* Wm    = (const float*)d_in[2];   // [4,4]
  const float* bv    = (const float*)d_in[3];   // [4]
  float* Dcoef = (float*)d_ws;                  // 81*4 floats
  const int B = in_sizes[0] / 4;

  hipLaunchKernelGGL(qg_precompute, dim3(1), dim3(256), 0, stream, qw, Wm, bv, Dcoef);

  const int blocks = (B + 511) / 512;           // 2048 for B = 1048576
  hipLaunchKernelGGL(qg_main, dim3(blocks), dim3(256), 0, stream,
                     (const float4*)noise, (const float*)Dcoef, (float4*)d_out, B);
}